// Round 1
// 3409.967 us; speedup vs baseline: 1.3965x; 1.3965x over previous
//
#include <hip/hip_runtime.h>

#define HD 1024
#define SQ 512
#define NHEAD 16
#define FFD 4096
#define NLAYER 12

typedef __attribute__((ext_vector_type(4))) float f32x4;
typedef __attribute__((ext_vector_type(8))) __bf16 bf16x8;

__device__ __forceinline__ short f2bf(float f) {
    union { float f; unsigned u; } v; v.f = f;
    unsigned r = v.u + 0x7fffu + ((v.u >> 16) & 1u);
    return (short)(r >> 16);
}
__device__ __forceinline__ float bf2f(short s) {
    union { unsigned u; float f; } v;
    v.u = ((unsigned)(unsigned short)s) << 16;
    return v.f;
}
__device__ __forceinline__ float lo2f(unsigned u) {
    union { unsigned u; float f; } v; v.u = u << 16; return v.f;
}
__device__ __forceinline__ float hi2f(unsigned u) {
    union { unsigned u; float f; } v; v.u = u & 0xffff0000u; return v.f;
}
__device__ __forceinline__ unsigned pk2(short a, short b) {
    return ((unsigned)(unsigned short)a) | (((unsigned)(unsigned short)b) << 16);
}
__device__ __forceinline__ void cp16bf(short* dst, const short* src) {
    uint4 u0 = *(const uint4*)src; uint4 u1 = *(const uint4*)(src + 8);
    *(uint4*)dst = u0; *(uint4*)(dst + 8) = u1;
}
__device__ __forceinline__ void cp32bf(short* dst, const short* src) {
    uint4 u0 = *(const uint4*)src;        uint4 u1 = *(const uint4*)(src + 8);
    uint4 u2 = *(const uint4*)(src + 16); uint4 u3 = *(const uint4*)(src + 24);
    *(uint4*)dst = u0; *(uint4*)(dst + 8) = u1;
    *(uint4*)(dst + 16) = u2; *(uint4*)(dst + 24) = u3;
}
__device__ __forceinline__ float wave_sum(float x) {
    #pragma unroll
    for (int o = 32; o > 0; o >>= 1) x += __shfl_xor(x, o, 64);
    return x;
}
__device__ __forceinline__ float wave_max(float x) {
    #pragma unroll
    for (int o = 32; o > 0; o >>= 1) x = fmaxf(x, __shfl_xor(x, o, 64));
    return x;
}
// async global -> LDS, 16B per lane; lds must be wave-uniform base.
__device__ __forceinline__ void gll16(const short* g, short* l) {
    __builtin_amdgcn_global_load_lds(
        (const __attribute__((address_space(1))) unsigned int*)g,
        (__attribute__((address_space(3))) unsigned int*)l, 16, 0, 0);
}

// ---------------- f32 -> bf16 bulk convert (n multiple of 2048*... of 8) ----------------
__global__ __launch_bounds__(256) void conv_bf16_kernel(
    const float* __restrict__ src, short* __restrict__ dst, int n)
{
    int i = (blockIdx.x * 256 + threadIdx.x) * 8;
    if (i >= n) return;
    float4 a = *(const float4*)(src + i);
    float4 b = *(const float4*)(src + i + 4);
    uint4 u;
    u.x = pk2(f2bf(a.x), f2bf(a.y)); u.y = pk2(f2bf(a.z), f2bf(a.w));
    u.z = pk2(f2bf(b.x), f2bf(b.y)); u.w = pk2(f2bf(b.z), f2bf(b.w));
    *(uint4*)(dst + i) = u;
}

// ---------------- embedding gather + LayerNorm * mask (f32 + bf16 out) ----------------
__global__ __launch_bounds__(256) void embed_ln_kernel(
    const int* __restrict__ ids, const int* __restrict__ mask,
    const float* __restrict__ we, const float* __restrict__ s,
    const float* __restrict__ b, float* __restrict__ h, short* __restrict__ hb)
{
    const int tok = blockIdx.x;
    const int tid = threadIdx.x, lane = tid & 63, w = tid >> 6;
    const float* row = we + (size_t)ids[tok] * HD;
    float4 v = *(const float4*)(row + tid * 4);
    __shared__ float red[8];
    float sm = wave_sum(v.x + v.y + v.z + v.w);
    float sq = wave_sum(v.x * v.x + v.y * v.y + v.z * v.z + v.w * v.w);
    if (!lane) { red[w] = sm; red[4 + w] = sq; }
    __syncthreads();
    float mean = (red[0] + red[1] + red[2] + red[3]) * (1.f / 1024.f);
    float var = (red[4] + red[5] + red[6] + red[7]) * (1.f / 1024.f) - mean * mean;
    float rs = rsqrtf(var + 1e-7f);
    float m = (float)mask[tok];
    float4 sv = *(const float4*)(s + tid * 4);
    float4 bv = *(const float4*)(b + tid * 4);
    float4 o;
    o.x = ((v.x - mean) * rs * sv.x + bv.x) * m;
    o.y = ((v.y - mean) * rs * sv.y + bv.y) * m;
    o.z = ((v.z - mean) * rs * sv.z + bv.z) * m;
    o.w = ((v.w - mean) * rs * sv.w + bv.w) * m;
    *(float4*)(h + (size_t)tok * HD + tid * 4) = o;
    uint2 pb; pb.x = pk2(f2bf(o.x), f2bf(o.y)); pb.y = pk2(f2bf(o.z), f2bf(o.w));
    *(uint2*)(hb + (size_t)tok * HD + tid * 4) = pb;
}

// ---------------- LayerNorm (f32 + bf16 out) ----------------
__global__ __launch_bounds__(256) void ln_kernel(
    const float* __restrict__ x, const float* __restrict__ s,
    const float* __restrict__ b, float* __restrict__ o, short* __restrict__ ob, float eps)
{
    const int row = blockIdx.x, tid = threadIdx.x, lane = tid & 63, w = tid >> 6;
    float4 v = *(const float4*)(x + (size_t)row * HD + tid * 4);
    __shared__ float red[8];
    float sm = wave_sum(v.x + v.y + v.z + v.w);
    float sq = wave_sum(v.x * v.x + v.y * v.y + v.z * v.z + v.w * v.w);
    if (!lane) { red[w] = sm; red[4 + w] = sq; }
    __syncthreads();
    float mean = (red[0] + red[1] + red[2] + red[3]) * (1.f / 1024.f);
    float var = (red[4] + red[5] + red[6] + red[7]) * (1.f / 1024.f) - mean * mean;
    float rs = rsqrtf(var + eps);
    float4 sv = *(const float4*)(s + tid * 4);
    float4 bv = *(const float4*)(b + tid * 4);
    float4 ov;
    ov.x = (v.x - mean) * rs * sv.x + bv.x;
    ov.y = (v.y - mean) * rs * sv.y + bv.y;
    ov.z = (v.z - mean) * rs * sv.z + bv.z;
    ov.w = (v.w - mean) * rs * sv.w + bv.w;
    *(float4*)(o + (size_t)row * HD + tid * 4) = ov;
    uint2 pb; pb.x = pk2(f2bf(ov.x), f2bf(ov.y)); pb.y = pk2(f2bf(ov.z), f2bf(ov.w));
    *(uint2*)(ob + (size_t)row * HD + tid * 4) = pb;
}

// ---------------- GEMM (bf16 in): C[M,N] = (A[M,K] @ W[N,K]^T + bias)*alpha ... ----------------
// flags: 1=bias, 2=residual(f32 R), 4=gelu, 8=store bf16 (Cb) else f32 (Cf).
// z-batched via wstride/bstride/cstride (elements). 64x64 tile, global_load_lds staging,
// 3-buffer 2-deep prefetch, counted vmcnt (never 0 mid-loop), raw s_barrier.
__global__ __launch_bounds__(256) void gemm_bf(
    const short* __restrict__ A, const short* __restrict__ W,
    const float* __restrict__ bias, const float* __restrict__ R,
    float* __restrict__ Cf, short* __restrict__ Cb,
    int M, int N, int K, int flags, float alpha,
    long wstride, long bstride, long cstride)
{
    __shared__ __align__(16) short As[3][64 * 64];
    __shared__ __align__(16) short Bs[3][64 * 64];
    const int tid = threadIdx.x, lane = tid & 63, w = tid >> 6;
    const int quad = lane >> 4, l15 = lane & 15;
    const int z = blockIdx.z;
    const int n0 = blockIdx.x * 64, m0 = blockIdx.y * 64;
    const int lrow = lane >> 3, gcol = (lane & 7) * 8;
    const short* Wz = W + (size_t)z * wstride;
    const short* Agp = A + (size_t)(m0 + w * 16 + lrow) * K + gcol;
    const short* Wgp = Wz + (size_t)(n0 + w * 16 + lrow) * K + gcol;

    f32x4 acc[4];
    #pragma unroll
    for (int i = 0; i < 4; i++) acc[i] = (f32x4){0.f, 0.f, 0.f, 0.f};

    auto STAGE = [&](int buf, int k0) {
        const short* ag = Agp + k0;
        const short* wg = Wgp + k0;
        gll16(ag,         &As[buf][(w * 16) * 64]);
        gll16(ag + 8 * K, &As[buf][(w * 16 + 8) * 64]);
        gll16(wg,         &Bs[buf][(w * 16) * 64]);
        gll16(wg + 8 * K, &Bs[buf][(w * 16 + 8) * 64]);
    };

    const int nk = K >> 6;
    STAGE(0, 0);
    if (nk > 1) STAGE(1, 64);
    for (int kt = 0; kt < nk; ++kt) {
        const int cur = kt % 3;
        if (kt + 2 < nk) {
            STAGE((kt + 2) % 3, (kt + 2) << 6);
            asm volatile("s_waitcnt vmcnt(8)" ::: "memory");
        } else if (kt + 1 < nk) {
            asm volatile("s_waitcnt vmcnt(4)" ::: "memory");
        } else {
            asm volatile("s_waitcnt vmcnt(0)" ::: "memory");
        }
        __builtin_amdgcn_s_barrier();
        __builtin_amdgcn_sched_barrier(0);
        #pragma unroll
        for (int ks = 0; ks < 2; ks++) {
            bf16x8 bfr = *(const bf16x8*)&Bs[cur][(w * 16 + l15) * 64 + ks * 32 + quad * 8];
            #pragma unroll
            for (int mt = 0; mt < 4; mt++) {
                bf16x8 afr = *(const bf16x8*)&As[cur][(mt * 16 + l15) * 64 + ks * 32 + quad * 8];
                acc[mt] = __builtin_amdgcn_mfma_f32_16x16x32_bf16(afr, bfr, acc[mt], 0, 0, 0);
            }
        }
        __builtin_amdgcn_s_barrier();
        __builtin_amdgcn_sched_barrier(0);
    }

    const int n = n0 + w * 16 + l15;
    const float bv = (flags & 1) ? bias[(size_t)z * bstride + n] : 0.f;
    #pragma unroll
    for (int mt = 0; mt < 4; mt++) {
        const int m = m0 + mt * 16 + quad * 4;
        #pragma unroll
        for (int r = 0; r < 4; r++) {
            float v = (acc[mt][r] + bv) * alpha;
            if (flags & 4) {
                float x = v;
                v = 0.5f * x * (1.f + tanhf(0.7978845608028654f * (x + 0.044715f * x * x * x)));
            }
            const size_t idx = (size_t)z * cstride + (size_t)(m + r) * N + n;
            if (flags & 2) v += R[idx];
            if (flags & 8) Cb[idx] = f2bf(v);
            else Cf[idx] = v;
        }
    }
}

// ---------------- attention scores: qk + c2p + p2c (bf16 qkv / pk / pq) ----------------
__global__ __launch_bounds__(256) void scores_kernel(
    const short* __restrict__ qkv, const float* __restrict__ qb,
    const short* __restrict__ pk, const short* __restrict__ pq,
    float* __restrict__ sc)
{
    __shared__ __align__(16) short s0[64 * 72];   // Q (ph1-2), K (ph3)
    __shared__ __align__(16) short s1[128 * 72];  // K / PK / PQ
    __shared__ float s2a[64 * 65];                // S1 accum + combine
    __shared__ short s2b[64 * 132];               // S2 / S3 (bf16)
    const int tid = threadIdx.x, lane = tid & 63, w = tid >> 6;
    const int quad = lane >> 4, l15 = lane & 15;
    const int qt = blockIdx.x, hh = blockIdx.y, b = blockIdx.z;
    const int q0 = qt * 64;
    const int srow = tid >> 2, scol = (tid & 3) << 4;
    const int prow = tid >> 1, pcol = (tid & 1) << 5;
    const int cqi = tid >> 2, ck0 = (tid & 3) << 4;
    const short* qsrc = qkv + (size_t)(b * SQ + q0 + srow) * (3 * HD) + hh * 192 + scol;
    const float* qbp = qb + hh * 64 + scol;
    const float iscale = 0.07216878364870322f;  // 1/sqrt(192)

    for (int kb = 0; kb < 8; kb++) {
        const int kbase = kb * 64;
        const int dbase = q0 - kbase + 449;
        const short* ksrc = qkv + (size_t)(b * SQ + kbase + srow) * (3 * HD) + hh * 192 + 64 + scol;
        __syncthreads();
        {   // stage Q -> s0 (bias+scale), K -> s1 (rows 0..63)
            uint4 uq0 = *(const uint4*)qsrc;
            uint4 uq1 = *(const uint4*)(qsrc + 8);
            float4 b0 = *(const float4*)(qbp);
            float4 b1 = *(const float4*)(qbp + 4);
            float4 b2 = *(const float4*)(qbp + 8);
            float4 b3 = *(const float4*)(qbp + 12);
            uint4 o0, o1;
            o0.x = pk2(f2bf((lo2f(uq0.x) + b0.x) * iscale), f2bf((hi2f(uq0.x) + b0.y) * iscale));
            o0.y = pk2(f2bf((lo2f(uq0.y) + b0.z) * iscale), f2bf((hi2f(uq0.y) + b0.w) * iscale));
            o0.z = pk2(f2bf((lo2f(uq0.z) + b1.x) * iscale), f2bf((hi2f(uq0.z) + b1.y) * iscale));
            o0.w = pk2(f2bf((lo2f(uq0.w) + b1.z) * iscale), f2bf((hi2f(uq0.w) + b1.w) * iscale));
            o1.x = pk2(f2bf((lo2f(uq1.x) + b2.x) * iscale), f2bf((hi2f(uq1.x) + b2.y) * iscale));
            o1.y = pk2(f2bf((lo2f(uq1.y) + b2.z) * iscale), f2bf((hi2f(uq1.y) + b2.w) * iscale));
            o1.z = pk2(f2bf((lo2f(uq1.z) + b3.x) * iscale), f2bf((hi2f(uq1.z) + b3.y) * iscale));
            o1.w = pk2(f2bf((lo2f(uq1.w) + b3.z) * iscale), f2bf((hi2f(uq1.w) + b3.w) * iscale));
            *(uint4*)&s0[srow * 72 + scol] = o0;
            *(uint4*)&s0[srow * 72 + scol + 8] = o1;
            cp16bf(&s1[srow * 72 + scol], ksrc);
        }
        __syncthreads();
        {   // S1 = Q @ K^T -> s2a (f32)
            f32x4 a1[4];
            #pragma unroll
            for (int i = 0; i < 4; i++) a1[i] = (f32x4){0.f, 0.f, 0.f, 0.f};
            #pragma unroll
            for (int ks = 0; ks < 2; ks++) {
                bf16x8 bfr = *(const bf16x8*)&s1[(w * 16 + l15) * 72 + ks * 32 + quad * 8];
                #pragma unroll
                for (int mt = 0; mt < 4; mt++) {
                    bf16x8 afr = *(const bf16x8*)&s0[(mt * 16 + l15) * 72 + ks * 32 + quad * 8];
                    a1[mt] = __builtin_amdgcn_mfma_f32_16x16x32_bf16(afr, bfr, a1[mt], 0, 0, 0);
                }
            }
            #pragma unroll
            for (int mt = 0; mt < 4; mt++)
                #pragma unroll
                for (int r = 0; r < 4; r++)
                    s2a[(mt * 16 + quad * 4 + r) * 65 + w * 16 + l15] = a1[mt][r];
        }
        __syncthreads();
        {   // stage PK window -> s1 (128 rows, bf16 copy)
            int gr = dbase + prow; if (gr > 1023) gr = 1023;
            cp32bf(&s1[prow * 72 + pcol], pk + (size_t)gr * HD + hh * 64 + pcol);
        }
        __syncthreads();
        {   // S2 = Q @ PK^T -> s2b (bf16)
            #pragma unroll
            for (int t2 = 0; t2 < 2; t2++) {
                const int nt = w + t2 * 4;
                f32x4 a2[4];
                #pragma unroll
                for (int i = 0; i < 4; i++) a2[i] = (f32x4){0.f, 0.f, 0.f, 0.f};
                #pragma unroll
                for (int ks = 0; ks < 2; ks++) {
                    bf16x8 bfr = *(const bf16x8*)&s1[(nt * 16 + l15) * 72 + ks * 32 + quad * 8];
                    #pragma unroll
                    for (int mt = 0; mt < 4; mt++) {
                        bf16x8 afr = *(const bf16x8*)&s0[(mt * 16 + l15) * 72 + ks * 32 + quad * 8];
                        a2[mt] = __builtin_amdgcn_mfma_f32_16x16x32_bf16(afr, bfr, a2[mt], 0, 0, 0);
                    }
                }
                #pragma unroll
                for (int mt = 0; mt < 4; mt++)
                    #pragma unroll
                    for (int r = 0; r < 4; r++)
                        s2b[(mt * 16 + quad * 4 + r) * 132 + nt * 16 + l15] = f2bf(a2[mt][r]);
            }
        }
        __syncthreads();
        {   // combine2: s2a[qi][kj] += S2[qi][qi-kj+63]
            #pragma unroll
            for (int j = 0; j < 16; j++) {
                const int kj = ck0 + j;
                s2a[cqi * 65 + kj] += bf2f(s2b[cqi * 132 + (cqi - kj + 63)]);
            }
        }
        __syncthreads();
        {   // stage K -> s0, PQ window -> s1
            cp16bf(&s0[srow * 72 + scol], ksrc);
            int gr = dbase + prow; if (gr > 1023) gr = 1023;
            cp32bf(&s1[prow * 72 + pcol], pq + (size_t)gr * HD + hh * 64 + pcol);
        }
        __syncthreads();
        {   // S3 = K @ PQ^T -> s2b (bf16)
            #pragma unroll
            for (int t2 = 0; t2 < 2; t2++) {
                const int nt = w + t2 * 4;
                f32x4 a3[4];
                #pragma unroll
                for (int i = 0; i < 4; i++) a3[i] = (f32x4){0.f, 0.f, 0.f, 0.f};
                #pragma unroll
                for (int ks = 0; ks < 2; ks++) {
                    bf16x8 bfr = *(const bf16x8*)&s1[(nt * 16 + l15) * 72 + ks * 32 + quad * 8];
                    #pragma unroll
                    for (int mt = 0; mt < 4; mt++) {
                        bf16x8 afr = *(const bf16x8*)&s0[(mt * 16 + l15) * 72 + ks * 32 + quad * 8];
                        a3[mt] = __builtin_amdgcn_mfma_f32_16x16x32_bf16(afr, bfr, a3[mt], 0, 0, 0);
                    }
                }
                #pragma unroll
                for (int mt = 0; mt < 4; mt++)
                    #pragma unroll
                    for (int r = 0; r < 4; r++)
                        s2b[(mt * 16 + quad * 4 + r) * 132 + nt * 16 + l15] = f2bf(a3[mt][r]);
            }
        }
        __syncthreads();
        {   // combine3 + global write
            float* outp = sc + ((size_t)((b * NHEAD + hh) * SQ + q0 + cqi)) * SQ + kbase;
            #pragma unroll
            for (int j = 0; j < 16; j++) {
                const int kj = ck0 + j;
                outp[kj] = s2a[cqi * 65 + kj] + bf2f(s2b[kj * 132 + (cqi - kj + 63)]);
            }
        }
    }
}

// ---------------- softmax (+mask) -> bf16 probs ----------------
__global__ __launch_bounds__(256) void softmax_kernel(
    const float* __restrict__ sc, const int* __restrict__ mask,
    unsigned short* __restrict__ probs)
{
    const int tid = threadIdx.x, lane = tid & 63, w = tid >> 6;
    const int row = blockIdx.x * 4 + w;   // (b*16+h)*512 + qi
    const int b = row >> 13;
    const int qi = row & 511;
    const float* x = sc + (size_t)row * SQ + lane * 8;
    float4 v1 = *(const float4*)x;
    float4 v2 = *(const float4*)(x + 4);
    float xv[8] = {v1.x, v1.y, v1.z, v1.w, v2.x, v2.y, v2.z, v2.w};
    const float mq = (float)mask[b * SQ + qi];
    const int* mrow = mask + b * SQ + lane * 8;
    float mk[8];
    #pragma unroll
    for (int j = 0; j < 8; j++) {
        mk[j] = (float)mrow[j];
        xv[j] = mk[j] > 0.f ? xv[j] : -1e9f;
    }
    float mx = xv[0];
    #pragma unroll
    for (int j = 1; j < 8; j++) mx = fmaxf(mx, xv[j]);
    mx = wave_max(mx);
    float e[8], sm = 0.f;
    #pragma unroll
    for (int j = 0; j < 8; j++) { e[j] = __expf(xv[j] - mx); sm += e[j]; }
    sm = wave_sum(sm);
    const float inv = 1.f / sm;
    uint4 u;
    short p[8];
    #pragma unroll
    for (int j = 0; j < 8; j++) p[j] = f2bf(e[j] * inv * mk[j] * mq);
    u.x = pk2(p[0], p[1]); u.y = pk2(p[2], p[3]); u.z = pk2(p[4], p[5]); u.w = pk2(p[6], p[7]);
    *(uint4*)(probs + (size_t)row * SQ + lane * 8) = u;
}

// ---------------- PV: ctx = probs @ V (bf16 qkv, bf16 ctx out) ----------------
__global__ __launch_bounds__(256) void pv_kernel(
    const unsigned short* __restrict__ probs, const short* __restrict__ qkv,
    const float* __restrict__ vb, short* __restrict__ ctx)
{
    __shared__ __align__(16) short Ps[64 * 40];
    __shared__ __align__(16) short Vs[64 * 40];
    const int tid = threadIdx.x, lane = tid & 63, w = tid >> 6;
    const int quad = lane >> 4, l15 = lane & 15;
    const int qt = blockIdx.x, hh = blockIdx.y, b = blockIdx.z;
    const int q0 = qt * 64;
    const int prow = tid >> 2, pcol = (tid & 3) << 3;
    const int vkj = tid & 31, vd0 = (tid >> 5) << 3;
    const unsigned short* pbase = probs + ((size_t)((b * NHEAD + hh) * SQ + q0 + prow)) * SQ + pcol;
    const short* vbase = qkv + (size_t)(b * SQ + vkj) * (3 * HD) + hh * 192 + 128 + vd0;
    float4 vb0 = *(const float4*)(vb + hh * 64 + vd0);
    float4 vb1 = *(const float4*)(vb + hh * 64 + vd0 + 4);
    f32x4 acc[4];
    #pragma unroll
    for (int i = 0; i < 4; i++) acc[i] = (f32x4){0.f, 0.f, 0.f, 0.f};
    for (int kb = 0; kb < 16; kb++) {
        __syncthreads();
        *(uint4*)&Ps[prow * 40 + pcol] = *(const uint4*)(pbase + kb * 32);
        const short* vs = vbase + (size_t)kb * 32 * (3 * HD);
        uint4 uv = *(const uint4*)vs;  // 8 bf16
        Vs[(vd0 + 0) * 40 + vkj] = f2bf(lo2f(uv.x) + vb0.x);
        Vs[(vd0 + 1) * 40 + vkj] = f2bf(hi2f(uv.x) + vb0.y);
        Vs[(vd0 + 2) * 40 + vkj] = f2bf(lo2f(uv.y) + vb0.z);
        Vs[(vd0 + 3) * 40 + vkj] = f2bf(hi2f(uv.y) + vb0.w);
        Vs[(vd0 + 4) * 40 + vkj] = f2bf(lo2f(uv.z) + vb1.x);
        Vs[(vd0 + 5) * 40 + vkj] = f2bf(hi2f(uv.z) + vb1.y);
        Vs[(vd0 + 6) * 40 + vkj] = f2bf(lo2f(uv.w) + vb1.z);
        Vs[(vd0 + 7) * 40 + vkj] = f2bf(hi2f(uv.w) + vb1.w);
        __syncthreads();
        bf16x8 bfr = *(const bf16x8*)&Vs[(w * 16 + l15) * 40 + quad * 8];
        #pragma unroll
        for (int mt = 0; mt < 4; mt++) {
            bf16x8 afr = *(const bf16x8*)&Ps[(mt * 16 + l15) * 40 + quad * 8];
            acc[mt] = __builtin_amdgcn_mfma_f32_16x16x32_bf16(afr, bfr, acc[mt], 0, 0, 0);
        }
    }
    #pragma unroll
    for (int mt = 0; mt < 4; mt++)
        #pragma unroll
        for (int r = 0; r < 4; r++)
            ctx[(size_t)(b * SQ + q0 + mt * 16 + quad * 4 + r) * HD + hh * 64 + w * 16 + l15]
                = f2bf(acc[mt][r]);
}

// ---------------- final head: LN(cls, eps=1e-5) @ out_w^T + out_b ----------------
__global__ __launch_bounds__(256) void head_kernel(
    const float* __restrict__ h, const float* __restrict__ s,
    const float* __restrict__ b, const float* __restrict__ ow,
    const float* __restrict__ ob, float* __restrict__ out)
{
    const int bb = blockIdx.x, tid = threadIdx.x, lane = tid & 63, w = tid >> 6;
    const float* x = h + (size_t)bb * SQ * HD;
    float4 v = *(const float4*)(x + tid * 4);
    __shared__ float red[8];
    float sm = wave_sum(v.x + v.y + v.z + v.w);
    float sq = wave_sum(v.x * v.x + v.y * v.y + v.z * v.z + v.w * v.w);
    if (!lane) { red[w] = sm; red[4 + w] = sq; }
    __syncthreads();
    float mean = (red[0] + red[1] + red[2] + red[3]) * (1.f / 1024.f);
    float var = (red[4] + red[5] + red[6] + red[7]) * (1.f / 1024.f) - mean * mean;
    float rs = rsqrtf(var + 1e-5f);
    float4 sv = *(const float4*)(s + tid * 4);
    float4 bv = *(const float4*)(b + tid * 4);
    float4 ov = *(const float4*)(ow + tid * 4);
    float d = ((v.x - mean) * rs * sv.x + bv.x) * ov.x
            + ((v.y - mean) * rs * sv.y + bv.y) * ov.y
            + ((v.z - mean) * rs * sv.z + bv.z) * ov.z
            + ((v.w - mean) * rs * sv.w + bv.w) * ov.w;
    d = wave_sum(d);
    __syncthreads();
    if (!lane) red[w] = d;
    __syncthreads();
    if (tid == 0) out[bb] = red[0] + red[1] + red[2] + red[3] + ob[0];
}

extern "C" void kernel_launch(void* const* d_in, const int* in_sizes, int n_in,
                              void* d_out, int out_size, void* d_ws, size_t ws_size,
                              hipStream_t stream) {
    (void)in_sizes; (void)n_in; (void)out_size; (void)ws_size;
    const int* ids        = (const int*)d_in[0];
    const int* mask       = (const int*)d_in[1];
    const float* word_emb = (const float*)d_in[3];
    const float* emb_ln_s = (const float*)d_in[4];
    const float* emb_ln_b = (const float*)d_in[5];
    const float* rel_emb  = (const float*)d_in[6];
    const float* in_w     = (const float*)d_in[7];
    const float* q_bias   = (const float*)d_in[8];
    const float* v_bias   = (const float*)d_in[9];
    const float* pos_k_w  = (const float*)d_in[10];
    const float* pos_q_w  = (const float*)d_in[11];
    const float* pos_q_b  = (const float*)d_in[12];
    const float* attn_o_w = (const float*)d_in[13];
    const float* attn_o_b = (const float*)d_in[14];
    const float* ln1_s    = (const float*)d_in[15];
    const float* ln1_b    = (const float*)d_in[16];
    const float* ffn_w1   = (const float*)d_in[17];
    const float* ffn_b1   = (const float*)d_in[18];
    const float* ffn_w2   = (const float*)d_in[19];
    const float* ffn_b2   = (const float*)d_in[20];
    const float* ln2_s    = (const float*)d_in[21];
    const float* ln2_b    = (const float*)d_in[22];
    const float* head_ln_s = (const float*)d_in[23];
    const float* head_ln_b = (const float*)d_in[24];
    const float* out_w    = (const float*)d_in[25];
    const float* out_b    = (const float*)d_in[26];
    float* out = (float*)d_out;
    float* ws = (float*)d_ws;

    const size_t M1 = 1024 * 1024;
    // f32 buffers
    float* h    = ws;                               // 1 M1
    float* t    = ws + M1;                          // 1 M1
    // bf16 activation buffers
    short* hb     = (short*)(ws + 2 * M1);          // 1M shorts
    short* qkvb   = (short*)(ws + (5 * M1) / 2);    // 3M shorts
    short* ctxb   = (short*)(ws + 4 * M1);          // 1M shorts
    short* ffb    = (short*)(ws + (9 * M1) / 2);    // 4M shorts
    float* scb    = ws + (13 * M1) / 2;             // 32x512x512 f32 (8 M1)
    unsigned short* probs = (unsigned short*)(ws + (29 * M1) / 2);  // 8M shorts (4 M1)
    // bf16 positional buffers (all layers, persistent across loop)
    short* pkball  = (short*)(ws + (37 * M1) / 2);  // 12M shorts
    short* pqball  = (short*)(ws + (49 * M1) / 2);  // 12M shorts
    short* relbf   = (short*)(ws + (61 * M1) / 2);  // 1M shorts
    short* poskwbf = (short*)(ws + 31 * M1);        // 12M shorts
    short* posqwbf = (short*)(ws + 37 * M1);        // 12M shorts
    // per-layer bf16 weight staging (reused each layer)
    short* inwbf  = (short*)(ws + 43 * M1);         // 3M shorts
    short* aowbf  = (short*)(ws + (89 * M1) / 2);   // 1M shorts
    short* w1bf   = (short*)(ws + 45 * M1);         // 4M shorts
    short* w2bf   = (short*)(ws + 47 * M1);         // 4M shorts  (end: 49 M1 = 196 MB)

    const float SCI = 0.07216878364870322f;  // 1/sqrt(192)

    embed_ln_kernel<<<dim3(1024), dim3(256), 0, stream>>>(ids, mask, word_emb, emb_ln_s, emb_ln_b, h, hb);

    // layer-invariant: convert rel/pos weights once, batched pos GEMMs for all 12 layers
    conv_bf16_kernel<<<dim3(512), dim3(256), 0, stream>>>(rel_emb, relbf, (int)M1);
    conv_bf16_kernel<<<dim3(6144), dim3(256), 0, stream>>>(pos_k_w, poskwbf, (int)(12 * M1));
    conv_bf16_kernel<<<dim3(6144), dim3(256), 0, stream>>>(pos_q_w, posqwbf, (int)(12 * M1));
    gemm_bf<<<dim3(16, 16, 12), dim3(256), 0, stream>>>(
        relbf, poskwbf, nullptr, nullptr, nullptr, pkball,
        1024, 1024, 1024, 8, 1.f, (long)M1, 0, (long)M1);
    gemm_bf<<<dim3(16, 16, 12), dim3(256), 0, stream>>>(
        relbf, posqwbf, pos_q_b, nullptr, nullptr, pqball,
        1024, 1024, 1024, 9, SCI, (long)M1, 1024, (long)M1);

    for (int l = 0; l < NLAYER; l++) {
        conv_bf16_kernel<<<dim3(1536), dim3(256), 0, stream>>>(in_w + (size_t)l * 3 * M1, inwbf, (int)(3 * M1));
        conv_bf16_kernel<<<dim3(512), dim3(256), 0, stream>>>(attn_o_w + (size_t)l * M1, aowbf, (int)M1);
        conv_bf16_kernel<<<dim3(2048), dim3(256), 0, stream>>>(ffn_w1 + (size_t)l * 4 * M1, w1bf, (int)(4 * M1));
        conv_bf16_kernel<<<dim3(2048), dim3(256), 0, stream>>>(ffn_w2 + (size_t)l * 4 * M1, w2bf, (int)(4 * M1));

        gemm_bf<<<dim3(48, 16), dim3(256), 0, stream>>>(
            hb, inwbf, nullptr, nullptr, nullptr, qkvb, 1024, 3072, 1024, 8, 1.f, 0, 0, 0);
        scores_kernel<<<dim3(8, 16, 2), dim3(256), 0, stream>>>(
            qkvb, q_bias + l * 1024, pkball + (size_t)l * M1, pqball + (size_t)l * M1, scb);
        softmax_kernel<<<dim3(4096), dim3(256), 0, stream>>>(scb, mask, probs);
        pv_kernel<<<dim3(8, 16, 2), dim3(256), 0, stream>>>(
            probs, qkvb, v_bias + l * 1024, ctxb);
        gemm_bf<<<dim3(16, 16), dim3(256), 0, stream>>>(
            ctxb, aowbf, attn_o_b + l * 1024, h, t, nullptr, 1024, 1024, 1024, 3, 1.f, 0, 0, 0);
        ln_kernel<<<dim3(1024), dim3(256), 0, stream>>>(t, ln1_s + l * 1024, ln1_b + l * 1024, h, hb, 1e-7f);
        gemm_bf<<<dim3(64, 16), dim3(256), 0, stream>>>(
            hb, w1bf, ffn_b1 + l * 4096, nullptr, nullptr, ffb, 1024, 4096, 1024, 13, 1.f, 0, 0, 0);
        gemm_bf<<<dim3(16, 16), dim3(256), 0, stream>>>(
            ffb, w2bf, ffn_b2 + l * 1024, h, t, nullptr, 1024, 1024, 4096, 3, 1.f, 0, 0, 0);
        ln_kernel<<<dim3(1024), dim3(256), 0, stream>>>(t, ln2_s + l * 1024, ln2_b + l * 1024, h, hb, 1e-7f);
    }
    head_kernel<<<dim3(2), dim3(256), 0, stream>>>(h, head_ln_s, head_ln_b, out_w, out_b, out);
}